// Round 1
// 1599.940 us; speedup vs baseline: 1.4131x; 1.4131x over previous
//
#include <hip/hip_runtime.h>
#include <cstdint>
#include <cstddef>

#define IN_F 512
#define OUT_F 1024
#define BATCH 8192
#define W_K 1535   // IN_F + OUT_F - 1
#define SROW 132   // padded t-dimension (16B-aligned rows, conflict-free quads)

typedef _Float16 half4 __attribute__((ext_vector_type(4)));

// ---------------------------------------------------------------------------
__global__ __launch_bounds__(256) void k_fill(float* __restrict__ out, float val) {
  const size_t i = ((size_t)blockIdx.x * 256 + threadIdx.x) * 4;
  float4 v; v.x = v.y = v.z = v.w = val;
  *(float4*)(out + i) = v;
}

// ---------------------------------------------------------------------------
// K1: xw = x @ Wx.T + bias mimicking numpy/OpenBLAS sgemm fp32 rounding:
// per C element ONE fp32 accumulator, FMA, k STRICTLY ascending (BLAS rank-1
// microkernel order; kc-blocking round-trips through fp32 exactly), then a
// single RNE add of bias. Intended to be bit-identical to np's xw.
// ---------------------------------------------------------------------------
__global__ __launch_bounds__(256) void k_gemm32(const float* __restrict__ x,
                                                const float* __restrict__ w,
                                                const float* __restrict__ bias,
                                                float* __restrict__ xw) {
  __shared__ float xs[64][33];
  __shared__ float wsh[64][33];
  const int t = threadIdx.x;
  const int bsub = t >> 4;    // 0..15 -> 4 b-rows
  const int esub = t & 15;    // 0..15 -> 4 e-cols
  const int bm = blockIdx.x;  // 128 tiles of 64 rows
  const int bn = blockIdx.y;  // 16 tiles of 64 cols
  const int srow = t >> 2;          // staging row 0..63
  const int scol = (t & 3) * 8;     // staging k-offset
  const float* xbase = x + (size_t)(bm * 64 + srow) * IN_F + scol;
  const float* wbase = w + (size_t)(bn * 64 + srow) * W_K + scol;

  float acc[4][4];
#pragma unroll
  for (int a = 0; a < 4; ++a)
#pragma unroll
    for (int b = 0; b < 4; ++b) acc[a][b] = 0.0f;

  for (int k0 = 0; k0 < IN_F; k0 += 32) {
    float xv[8], wv[8];
#pragma unroll
    for (int c = 0; c < 8; ++c) { xv[c] = xbase[k0 + c]; wv[c] = wbase[k0 + c]; }
    __syncthreads();
#pragma unroll
    for (int c = 0; c < 8; ++c) { xs[srow][scol + c] = xv[c]; wsh[srow][scol + c] = wv[c]; }
    __syncthreads();
#pragma unroll
    for (int k = 0; k < 32; ++k) {   // ascending k: exact BLAS accumulation order
      const float a0 = xs[bsub * 4 + 0][k], a1 = xs[bsub * 4 + 1][k];
      const float a2 = xs[bsub * 4 + 2][k], a3 = xs[bsub * 4 + 3][k];
      const float b0 = wsh[esub * 4 + 0][k], b1 = wsh[esub * 4 + 1][k];
      const float b2 = wsh[esub * 4 + 2][k], b3 = wsh[esub * 4 + 3][k];
      acc[0][0] = fmaf(a0, b0, acc[0][0]); acc[0][1] = fmaf(a0, b1, acc[0][1]);
      acc[0][2] = fmaf(a0, b2, acc[0][2]); acc[0][3] = fmaf(a0, b3, acc[0][3]);
      acc[1][0] = fmaf(a1, b0, acc[1][0]); acc[1][1] = fmaf(a1, b1, acc[1][1]);
      acc[1][2] = fmaf(a1, b2, acc[1][2]); acc[1][3] = fmaf(a1, b3, acc[1][3]);
      acc[2][0] = fmaf(a2, b0, acc[2][0]); acc[2][1] = fmaf(a2, b1, acc[2][1]);
      acc[2][2] = fmaf(a2, b2, acc[2][2]); acc[2][3] = fmaf(a2, b3, acc[2][3]);
      acc[3][0] = fmaf(a3, b0, acc[3][0]); acc[3][1] = fmaf(a3, b1, acc[3][1]);
      acc[3][2] = fmaf(a3, b2, acc[3][2]); acc[3][3] = fmaf(a3, b3, acc[3][3]);
    }
  }

#pragma unroll
  for (int ie = 0; ie < 4; ++ie) {
    const int e = bn * 64 + esub * 4 + ie;
    const float bv = bias[e];
#pragma unroll
    for (int ib = 0; ib < 4; ++ib) {
      const int b = bm * 64 + bsub * 4 + ib;
      xw[(size_t)b * OUT_F + e] = acc[ib][ie] + bv;   // single RNE add, like np
    }
  }
}

// ---------------------------------------------------------------------------
// K2: scan, same OpenBLAS sgemv_t fp32 semantics as before (8 mod-8 partials,
// ascending-j FMA chains, AVX tree, scalar tail, single RNE adds, fp64 σ),
// now fully software-pipelined inside the single wave:
//   - Wo row i+1 register-double-buffered: global->VGPR issued at step top,
//     VGPR->LDS after the dot/tail of step i consume row i (no barrier in a
//     1-wave block, so loads stay in flight under the compute).
//   - xw/u prefetched in double-buffered 32-step LDS chunks (kills the
//     per-step scalar global loads on the serial path).
//   - samples stored as fp16 (0.0/1.0 exact; v_cvt_f32_f16 exact => every
//     fmaf sees bit-identical operands). Unwritten entries zero => exact +0
//     contributions for overshoot quads, as before.
// LDS: 16.9K smph + 4.2K wop + 8K xwu + 0.25K tail = 29.5K < 40K => 4 blk/CU.
// ---------------------------------------------------------------------------
__global__ __launch_bounds__(64) void k_scan32(const float* __restrict__ w,
                                               const float* __restrict__ u,
                                               const float* __restrict__ xw,
                                               float* __restrict__ out_s,
                                               float* __restrict__ out_l) {
  __shared__ _Float16 smph[8][8][SROW];   // 16.9 KiB: sample s_{m+8t} of row g
  __shared__ float    wop[8][SROW];       // 4.2 KiB: permuted Wo row (j%8, j/8)
  __shared__ float    xwu[2][2][8][32];   // 8 KiB: [buf][xw|u][row][step%32]
  __shared__ float    tail_smp[8][8];     // samples j in [1016,1024)

  const int lane = threadIdx.x;
  const int g = lane >> 3;   // row group 0..7
  const int m = lane & 7;    // partial index

  // zero-init LDS (harness poisons; zeros are semantically exact filler)
  {
    uint32_t* p = (uint32_t*)&smph[0][0][0];
    for (int idx = lane; idx < 8 * 8 * SROW / 2; idx += 64) p[idx] = 0u;
    if (lane < 8) {
#pragma unroll
      for (int jj = 0; jj < 8; ++jj) tail_smp[lane][jj] = 0.0f;
    }
  }

  const int r = blockIdx.x * 8 + g;
  float* osr = out_s + (size_t)r * OUT_F;
  float* olr = out_l + (size_t)r * OUT_F;

  // ---- prologue: Wo row 0 -> regs -> LDS (permuted: wop[j%8][j/8]) ----
  float wv[16];
  {
    const float* wrow = w + (size_t)0 * W_K + IN_F;
#pragma unroll
    for (int c = 0; c < 16; ++c)
      wv[c] = (lane + 64 * c < OUT_F - 1) ? wrow[lane + 64 * c] : 0.0f;
#pragma unroll
    for (int c = 0; c < 16; ++c)
      wop[lane & 7][(lane >> 3) + 8 * c] = wv[c];
  }

  // ---- prologue: xw/u chunk 0 -> buf 0 ----
  {
    const int rr = blockIdx.x * 8 + (lane >> 3);
    const float4 xv = *(const float4*)(xw + (size_t)rr * OUT_F + 4 * (lane & 7));
    const float4 uv = *(const float4*)(u + (size_t)rr * OUT_F + 4 * (lane & 7));
    *(float4*)&xwu[0][0][lane >> 3][4 * (lane & 7)] = xv;
    *(float4*)&xwu[0][1][lane >> 3][4 * (lane & 7)] = uv;
  }

  float4 pxw{}, pu{};   // pending next-chunk regs (loaded cph==0, stored cph==16)

  for (int i = 0; i < OUT_F; ++i) {
    const int cph = i & 31;
    const int chunk = i >> 5;

    if (cph == 0) {   // issue next xw/u chunk (arrives over the next ~16 steps)
      const int cn = chunk + 1;
      const int cbase = (cn < 32 ? cn : 31) * 32;
      const int rr = blockIdx.x * 8 + (lane >> 3);
      pxw = *(const float4*)(xw + (size_t)rr * OUT_F + cbase + 4 * (lane & 7));
      pu  = *(const float4*)(u + (size_t)rr * OUT_F + cbase + 4 * (lane & 7));
    }

    // issue Wo row i+1 loads now; they complete under this step's compute
    {
      const int inext = (i + 1 < OUT_F) ? i + 1 : OUT_F - 1;
      const float* wrow = w + (size_t)inext * W_K + IN_F;
#pragma unroll
      for (int c = 0; c < 16; ++c)
        wv[c] = (lane + 64 * c < OUT_F - 1) ? wrow[lane + 64 * c] : 0.0f;
    }

    // vector-region partial P_m: j = m + 8t, ascending t, FMA (product exact;
    // overshoot quad entries are exact zeros)
    float P = 0.0f;
    const int ilim = (i < 1016) ? i : 1016;
    const int tcap = (ilim + 7) >> 3;
    const int qn = (tcap + 3) >> 2;
    const half4* sp = (const half4*)&smph[g][m][0];
    const float4* wp = (const float4*)&wop[m][0];
    for (int q = 0; q < qn; ++q) {
      const half4 s4 = sp[q];
      const float4 w4 = wp[q];
      P = fmaf((float)s4.x, w4.x, P);
      P = fmaf((float)s4.y, w4.y, P);
      P = fmaf((float)s4.z, w4.z, P);
      P = fmaf((float)s4.w, w4.w, P);
    }

    // AVX horizontal tree: ((P0+P4)+(P2+P6)) + ((P1+P5)+(P3+P7))
    float t1 = P + __shfl_xor(P, 4);
    float t2 = t1 + __shfl_xor(t1, 2);
    float T = t2 + __shfl_xor(t2, 1);

    // hoist row-i tail weights before wop is overwritten with row i+1
    float tw[7];
#pragma unroll
    for (int jj = 0; jj < 7; ++jj) tw[jj] = wop[jj][127];

    // stage Wo row i+1 regs -> LDS (row i fully consumed above)
#pragma unroll
    for (int c = 0; c < 16; ++c)
      wop[lane & 7][(lane >> 3) + 8 * c] = wv[c];

    if (cph == 16) {   // park the pending chunk in the other buffer
      *(float4*)&xwu[(chunk + 1) & 1][0][lane >> 3][4 * (lane & 7)] = pxw;
      *(float4*)&xwu[(chunk + 1) & 1][1][lane >> 3][4 * (lane & 7)] = pu;
    }

    if (m == 0) {
      // scalar tail j = 1016..1022, ascending (zeros exact when j>=i)
#pragma unroll
      for (int jj = 0; jj < 7; ++jj)
        T = fmaf(tail_smp[g][jj], tw[jj], T);
      const float xwi = xwu[chunk & 1][0][g][cph];
      const float ui  = xwu[chunk & 1][1][g][cph];
      const float L = xwi + T;                         // np: xw_i + dot
      const double sd = 1.0 / (1.0 + exp(-(double)L)); // σ, near-correctly-rounded
      const float sig = (float)sd;
      const float s = (ui < sig) ? 1.0f : 0.0f;
      if (i < 1016) smph[g][i & 7][i >> 3] = (_Float16)s;
      else tail_smp[g][i - 1016] = s;
      osr[i] = s;
      olr[i] = L;
    }
  }
}

// ---------------------------------------------------------------------------
extern "C" void kernel_launch(void* const* d_in, const int* in_sizes, int n_in,
                              void* d_out, int out_size, void* d_ws, size_t ws_size,
                              hipStream_t stream) {
  float* out_s = (float*)d_out;                      // samples (B x OUT_F) fp32
  float* out_l = out_s + (size_t)BATCH * OUT_F;      // logits  (B x OUT_F) fp32
  const int nfill = (BATCH * OUT_F) / (256 * 4);

  const bool shapes_ok =
      n_in == 4 &&
      in_sizes[0] == BATCH * IN_F && in_sizes[1] == OUT_F * W_K &&
      in_sizes[2] == OUT_F && in_sizes[3] == BATCH * OUT_F &&
      out_size == 2 * BATCH * OUT_F;
  if (!shapes_ok) {
    k_fill<<<nfill, 256, 0, stream>>>(out_s, 11.0f);
    return;
  }

  const size_t xw_bytes = (size_t)BATCH * OUT_F * sizeof(float);  // 32 MiB
  if (ws_size < xw_bytes) {
    k_fill<<<nfill, 256, 0, stream>>>(out_s, 7.0f);
    return;
  }

  const float* x = (const float*)d_in[0];     // fp32 (8192 x 512)
  const float* w = (const float*)d_in[1];     // fp32 (1024 x 1535)
  const float* bias = (const float*)d_in[2];  // fp32 (1024)
  const float* u = (const float*)d_in[3];     // fp32 (8192 x 1024)
  float* xw = (float*)d_ws;                   // 32 MiB

  k_gemm32<<<dim3(BATCH / 64, OUT_F / 64), 256, 0, stream>>>(x, w, bias, xw);
  k_scan32<<<BATCH / 8, 64, 0, stream>>>(w, u, xw, out_s, out_l);
}

// Round 2
// 1390.771 us; speedup vs baseline: 1.6256x; 1.1504x over previous
//
#include <hip/hip_runtime.h>
#include <cstdint>
#include <cstddef>

#define IN_F 512
#define OUT_F 1024
#define BATCH 8192
#define W_K 1535   // IN_F + OUT_F - 1
#define SROW 132   // padded t-dimension (16B-aligned rows)

typedef _Float16 half4 __attribute__((ext_vector_type(4)));

// ---------------------------------------------------------------------------
__global__ __launch_bounds__(256) void k_fill(float* __restrict__ out, float val) {
  const size_t i = ((size_t)blockIdx.x * 256 + threadIdx.x) * 4;
  float4 v; v.x = v.y = v.z = v.w = val;
  *(float4*)(out + i) = v;
}

// ---------------------------------------------------------------------------
// K1: xw = x @ Wx.T + bias, OpenBLAS sgemm fp32 semantics (one accumulator,
// ascending k, single RNE bias add). Unchanged from previous round.
// ---------------------------------------------------------------------------
__global__ __launch_bounds__(256) void k_gemm32(const float* __restrict__ x,
                                                const float* __restrict__ w,
                                                const float* __restrict__ bias,
                                                float* __restrict__ xw) {
  __shared__ float xs[64][33];
  __shared__ float wsh[64][33];
  const int t = threadIdx.x;
  const int bsub = t >> 4;
  const int esub = t & 15;
  const int bm = blockIdx.x;
  const int bn = blockIdx.y;
  const int srow = t >> 2;
  const int scol = (t & 3) * 8;
  const float* xbase = x + (size_t)(bm * 64 + srow) * IN_F + scol;
  const float* wbase = w + (size_t)(bn * 64 + srow) * W_K + scol;

  float acc[4][4];
#pragma unroll
  for (int a = 0; a < 4; ++a)
#pragma unroll
    for (int b = 0; b < 4; ++b) acc[a][b] = 0.0f;

  for (int k0 = 0; k0 < IN_F; k0 += 32) {
    float xv[8], wv[8];
#pragma unroll
    for (int c = 0; c < 8; ++c) { xv[c] = xbase[k0 + c]; wv[c] = wbase[k0 + c]; }
    __syncthreads();
#pragma unroll
    for (int c = 0; c < 8; ++c) { xs[srow][scol + c] = xv[c]; wsh[srow][scol + c] = wv[c]; }
    __syncthreads();
#pragma unroll
    for (int k = 0; k < 32; ++k) {
      const float a0 = xs[bsub * 4 + 0][k], a1 = xs[bsub * 4 + 1][k];
      const float a2 = xs[bsub * 4 + 2][k], a3 = xs[bsub * 4 + 3][k];
      const float b0 = wsh[esub * 4 + 0][k], b1 = wsh[esub * 4 + 1][k];
      const float b2 = wsh[esub * 4 + 2][k], b3 = wsh[esub * 4 + 3][k];
      acc[0][0] = fmaf(a0, b0, acc[0][0]); acc[0][1] = fmaf(a0, b1, acc[0][1]);
      acc[0][2] = fmaf(a0, b2, acc[0][2]); acc[0][3] = fmaf(a0, b3, acc[0][3]);
      acc[1][0] = fmaf(a1, b0, acc[1][0]); acc[1][1] = fmaf(a1, b1, acc[1][1]);
      acc[1][2] = fmaf(a1, b2, acc[1][2]); acc[1][3] = fmaf(a1, b3, acc[1][3]);
      acc[2][0] = fmaf(a2, b0, acc[2][0]); acc[2][1] = fmaf(a2, b1, acc[2][1]);
      acc[2][2] = fmaf(a2, b2, acc[2][2]); acc[2][3] = fmaf(a2, b3, acc[2][3]);
      acc[3][0] = fmaf(a3, b0, acc[3][0]); acc[3][1] = fmaf(a3, b1, acc[3][1]);
      acc[3][2] = fmaf(a3, b2, acc[3][2]); acc[3][3] = fmaf(a3, b3, acc[3][3]);
    }
  }

#pragma unroll
  for (int ie = 0; ie < 4; ++ie) {
    const int e = bn * 64 + esub * 4 + ie;
    const float bv = bias[e];
#pragma unroll
    for (int ib = 0; ib < 4; ++ib) {
      const int b = bm * 64 + bsub * 4 + ib;
      xw[(size_t)b * OUT_F + e] = acc[ib][ie] + bv;
    }
  }
}

// ---------------------------------------------------------------------------
// K2: scan with the sigmoid DECOUPLED from the dot of the next step.
// Bit-exactness argument:
//   - fmaf(+0,w,P) == P exactly, so the dot may read a zero at slot j=i-1 and
//     the real term s_{i-1}*w is appended at chain END via a register fixup:
//     all intervening terms are exact identities, so the value is bitwise
//     equal to the in-order chain.
//   - the butterfly tree gives bitwise-identical T on all 8 lanes of a group
//     (RNE add is commutative), so sigma runs replicated on all lanes: no
//     broadcast shuffle on the serial path.
//   - tail samples (j>=1016) live in replicated registers, ascending order
//     preserved; zeros are exact no-ops.
// Per step, the fp64 sigma chain of s_{i-1} and the dot chain of L_i are
// independent -> the scheduler interleaves them (ILP), critical path ~
// max(dot, sigma) + tree + fixup instead of their sum.
// ---------------------------------------------------------------------------
__global__ __launch_bounds__(64) void k_scan32(const float* __restrict__ w,
                                               const float* __restrict__ u,
                                               const float* __restrict__ xw,
                                               float* __restrict__ out_s,
                                               float* __restrict__ out_l) {
  __shared__ _Float16 smph[8][8][SROW];   // 16.9 KiB sample state (fp16 exact 0/1)
  __shared__ float    wop[8][SROW];       // 4.2 KiB permuted Wo row (j%8, j/8)
  __shared__ float    xwu[2][2][8][32];   // 8 KiB [buf][xw|u][row][step%32]

  const int lane = threadIdx.x;
  const int g = lane >> 3;   // row group 0..7
  const int m = lane & 7;    // partial index

  // zero-init sample state (zeros are exact +0 contributions)
  {
    uint32_t* p = (uint32_t*)&smph[0][0][0];
    for (int idx = lane; idx < 8 * 8 * SROW / 2; idx += 64) p[idx] = 0u;
  }

  const int r = blockIdx.x * 8 + g;
  float* osr = out_s + (size_t)r * OUT_F;
  float* olr = out_l + (size_t)r * OUT_F;

  // ---- prologue: xwu chunk 0 -> buf0; chunk 1 -> regs (parked at i=16) ----
  const int rr = blockIdx.x * 8 + (lane >> 3);
  {
    const float4 xv = *(const float4*)(xw + (size_t)rr * OUT_F + 4 * (lane & 7));
    const float4 uv = *(const float4*)(u  + (size_t)rr * OUT_F + 4 * (lane & 7));
    *(float4*)&xwu[0][0][lane >> 3][4 * (lane & 7)] = xv;
    *(float4*)&xwu[0][1][lane >> 3][4 * (lane & 7)] = uv;
  }
  float4 pxw = *(const float4*)(xw + (size_t)rr * OUT_F + 32 + 4 * (lane & 7));
  float4 pu  = *(const float4*)(u  + (size_t)rr * OUT_F + 32 + 4 * (lane & 7));

  // ---- prologue: Wo row 1 -> wop (permuted). wv[c] holds j = 4*lane+256*(c/4)+(c%4).
  float wv[16];
  {
    const float* wrow = w + (size_t)1 * W_K + IN_F;
#pragma unroll
    for (int c = 0; c < 3; ++c)
      *(float4*)&wv[4 * c] = *(const float4*)(wrow + 4 * lane + 256 * c);
    if (lane < 63) {
      *(float4*)&wv[12] = *(const float4*)(wrow + 4 * lane + 768);
    } else {
      wv[12] = wrow[1020]; wv[13] = wrow[1021]; wv[14] = wrow[1022]; wv[15] = 0.0f;
    }
#pragma unroll
    for (int c = 0; c < 16; ++c) {
      const int j = 4 * lane + 256 * (c >> 2) + (c & 3);
      wop[j & 7][j >> 3] = wv[c];
    }
  }

  // L_0 = xw_0 + (exact +0 dot over all-zero state)
  float L_prev = xwu[0][0][g][0];
  float u_prev = xwu[0][1][g][0];
  if (m == 0) olr[0] = L_prev;

  float tl[7];   // tail samples j in [1016,1023), replicated on all lanes
#pragma unroll
  for (int jj = 0; jj < 7; ++jj) tl[jj] = 0.0f;

  for (int i = 1; i < OUT_F; ++i) {
    const int cph = i & 31;
    const int chunk = i >> 5;

    if (cph == 0) {   // issue next xw/u chunk
      const int cn = chunk + 1;
      const int cbase = (cn < 32 ? cn : 31) * 32;
      pxw = *(const float4*)(xw + (size_t)rr * OUT_F + cbase + 4 * (lane & 7));
      pu  = *(const float4*)(u  + (size_t)rr * OUT_F + cbase + 4 * (lane & 7));
    }

    // issue Wo row i+1 global loads; they complete under this step's compute
    {
      const int inext = (i + 1 < OUT_F) ? i + 1 : OUT_F - 1;
      const float* wrow = w + (size_t)inext * W_K + IN_F;
#pragma unroll
      for (int c = 0; c < 3; ++c)
        *(float4*)&wv[4 * c] = *(const float4*)(wrow + 4 * lane + 256 * c);
      if (lane < 63) {
        *(float4*)&wv[12] = *(const float4*)(wrow + 4 * lane + 768);
      } else {
        wv[12] = wrow[1020]; wv[13] = wrow[1021]; wv[14] = wrow[1022]; wv[15] = 0.0f;
      }
    }

    // sigma for s_{i-1} — replicated on all lanes (L_prev/u_prev uniform per g).
    // Independent of the dot below: the two chains overlap in the issue stream.
    const double sd = 1.0 / (1.0 + exp(-(double)L_prev));   // near-correctly-rounded
    const float sig = (float)sd;
    const float s_prev = (u_prev < sig) ? 1.0f : 0.0f;

    // dot over LDS state (samples <= i-2; slot i-1 reads exact +0)
    float P = 0.0f;
    const int ilim = (i < 1016) ? i : 1016;
    const int tcap = (ilim + 7) >> 3;
    const int qn = (tcap + 3) >> 2;
    const half4* sp = (const half4*)&smph[g][m][0];
    const float4* wp = (const float4*)&wop[m][0];
    for (int q = 0; q < qn; ++q) {
      const half4 s4 = sp[q];
      const float4 w4 = wp[q];
      P = fmaf((float)s4.x, w4.x, P);
      P = fmaf((float)s4.y, w4.y, P);
      P = fmaf((float)s4.z, w4.z, P);
      P = fmaf((float)s4.w, w4.w, P);
    }

    // fixup: append the j=i-1 term at the end of its partial's chain (exact)
    const int jprev = i - 1;
    if (jprev < 1016) {
      const float wfix = wop[jprev & 7][jprev >> 3];       // uniform read, row i
      P = fmaf((m == (jprev & 7)) ? s_prev : 0.0f, wfix, P);
    } else {
      tl[jprev - 1016] = s_prev;                           // tail register update
    }

    // AVX horizontal tree: ((P0+P4)+(P2+P6)) + ((P1+P5)+(P3+P7)); all lanes
    // end with bitwise-identical T (RNE add commutes).
    float t1 = P + __shfl_xor(P, 4);
    float t2 = t1 + __shfl_xor(t1, 2);
    float T = t2 + __shfl_xor(t2, 1);

    // scalar tail j = 1016..1022 (row-i weights; read before restaging)
#pragma unroll
    for (int jj = 0; jj < 7; ++jj)
      T = fmaf(tl[jj], wop[jj][127], T);

    // L_i and next-step u (uniform per g)
    const float L = xwu[chunk & 1][0][g][cph] + T;         // np: xw_i + dot
    const float un = xwu[chunk & 1][1][g][cph];

    // restage wop with row i+1 (row i fully consumed above)
#pragma unroll
    for (int c = 0; c < 16; ++c) {
      const int j = 4 * lane + 256 * (c >> 2) + (c & 3);
      wop[j & 7][j >> 3] = wv[c];
    }

    if (cph == 16) {   // park pending xw/u chunk into the other buffer
      *(float4*)&xwu[(chunk + 1) & 1][0][lane >> 3][4 * (lane & 7)] = pxw;
      *(float4*)&xwu[(chunk + 1) & 1][1][lane >> 3][4 * (lane & 7)] = pu;
    }

    if (m == 0) {
      osr[jprev] = s_prev;
      olr[i] = L;
      if (jprev < 1016) smph[g][jprev & 7][jprev >> 3] = (_Float16)s_prev;
    }

    L_prev = L;
    u_prev = un;
  }

  // epilogue: sample 1023
  {
    const double sd = 1.0 / (1.0 + exp(-(double)L_prev));
    const float sig = (float)sd;
    const float s = (u_prev < sig) ? 1.0f : 0.0f;
    if (m == 0) osr[OUT_F - 1] = s;
  }
}

// ---------------------------------------------------------------------------
extern "C" void kernel_launch(void* const* d_in, const int* in_sizes, int n_in,
                              void* d_out, int out_size, void* d_ws, size_t ws_size,
                              hipStream_t stream) {
  float* out_s = (float*)d_out;                      // samples (B x OUT_F) fp32
  float* out_l = out_s + (size_t)BATCH * OUT_F;      // logits  (B x OUT_F) fp32
  const int nfill = (BATCH * OUT_F) / (256 * 4);

  const bool shapes_ok =
      n_in == 4 &&
      in_sizes[0] == BATCH * IN_F && in_sizes[1] == OUT_F * W_K &&
      in_sizes[2] == OUT_F && in_sizes[3] == BATCH * OUT_F &&
      out_size == 2 * BATCH * OUT_F;
  if (!shapes_ok) {
    k_fill<<<nfill, 256, 0, stream>>>(out_s, 11.0f);
    return;
  }

  const size_t xw_bytes = (size_t)BATCH * OUT_F * sizeof(float);  // 32 MiB
  if (ws_size < xw_bytes) {
    k_fill<<<nfill, 256, 0, stream>>>(out_s, 7.0f);
    return;
  }

  const float* x = (const float*)d_in[0];     // fp32 (8192 x 512)
  const float* w = (const float*)d_in[1];     // fp32 (1024 x 1535)
  const float* bias = (const float*)d_in[2];  // fp32 (1024)
  const float* u = (const float*)d_in[3];     // fp32 (8192 x 1024)
  float* xw = (float*)d_ws;                   // 32 MiB

  k_gemm32<<<dim3(BATCH / 64, OUT_F / 64), 256, 0, stream>>>(x, w, bias, xw);
  k_scan32<<<BATCH / 8, 64, 0, stream>>>(w, u, xw, out_s, out_l);
}